// Round 2
// baseline (4435.207 us; speedup 1.0000x reference)
//
#include <hip/hip_runtime.h>
#include <hip/hip_bf16.h>
#include <math.h>

// Problem constants
#define BB 4
#define LL 2048
#define DM 1024
#define DI 2048
#define DS 16
#define DR 64
#define KC 4
#define TT (BB * LL)   // 8192 tokens

typedef __hip_bfloat16 bf16;

__device__ __forceinline__ float cvt(float v) { return v; }
__device__ __forceinline__ float cvt(bf16 v) { return __bfloat162float(v); }
__device__ __forceinline__ void stv(float* p, float v) { *p = v; }
__device__ __forceinline__ void stv(bf16* p, float v) { *p = __float2bfloat16(v); }

// ---------------------------------------------------------------------------
// Generic GEMM: C[M,N] = A[M,K] * W[N,K]^T (+ optional softplus epilogue)
// A: TA (f32 or bf16), W: f32, C: TC. fp32 accumulate.
// BM=BN=64, BK=16, 256 threads, 4x4 per-thread microtile.
// EPI==1: C = softplus(acc + bias[n])
// ---------------------------------------------------------------------------
template <typename TA, typename TC, int EPI>
__global__ __launch_bounds__(256) void gemm_nt(
    const TA* __restrict__ A, int lda,
    const float* __restrict__ W,
    const float* __restrict__ bias,
    TC* __restrict__ C, int ldc,
    int M, int N, int Kd) {
  const int BM = 64, BN = 64, BK = 16;
  __shared__ float As[BK][BM + 1];
  __shared__ float Ws[BK][BN + 1];

  int bn = blockIdx.x * BN;
  int bm = blockIdx.y * BM;
  int tid = threadIdx.x;
  int tx = tid & 15;        // N direction
  int ty = tid >> 4;        // M direction
  float acc[4][4] = {};

  for (int k0 = 0; k0 < Kd; k0 += BK) {
#pragma unroll
    for (int p = 0; p < 4; ++p) {
      int r = (tid >> 4) + p * 16;
      int c = tid & 15;
      int gr = bm + r, gc = k0 + c;
      As[c][r] = (gr < M && gc < Kd) ? cvt(A[(size_t)gr * lda + gc]) : 0.f;
      int wr = bn + r;
      Ws[c][r] = (wr < N && gc < Kd) ? W[(size_t)wr * Kd + gc] : 0.f;
    }
    __syncthreads();
#pragma unroll
    for (int kk = 0; kk < BK; ++kk) {
      float a[4], w[4];
#pragma unroll
      for (int i = 0; i < 4; ++i) a[i] = As[kk][ty * 4 + i];
#pragma unroll
      for (int j = 0; j < 4; ++j) w[j] = Ws[kk][tx * 4 + j];
#pragma unroll
      for (int i = 0; i < 4; ++i)
#pragma unroll
        for (int j = 0; j < 4; ++j)
          acc[i][j] = fmaf(a[i], w[j], acc[i][j]);
    }
    __syncthreads();
  }

#pragma unroll
  for (int i = 0; i < 4; ++i) {
    int r = bm + ty * 4 + i;
    if (r >= M) continue;
#pragma unroll
    for (int j = 0; j < 4; ++j) {
      int c = bn + tx * 4 + j;
      if (c >= N) continue;
      float v = acc[i][j];
      if (EPI == 1) {
        v += bias[c];
        v = (v > 20.f) ? v : log1pf(expf(v));
      }
      stv(&C[(size_t)r * ldc + c], v);
    }
  }
}

// ---------------------------------------------------------------------------
// Depthwise causal conv1d (K=4) + bias + SiLU.
// x lives in the first DI columns of xz (bf16, row stride 2*DI).
// ---------------------------------------------------------------------------
__global__ __launch_bounds__(256) void conv_silu(
    const bf16* __restrict__ xz, const float* __restrict__ cw,
    const float* __restrict__ cb, bf16* __restrict__ u) {
  int d = blockIdx.x * 256 + threadIdx.x;  // 0..DI-1
  int t = blockIdx.y;                      // 0..TT-1
  int l = t & (LL - 1);
  float acc = cb[d];
#pragma unroll
  for (int k = 0; k < KC; ++k) {
    int lt = l - (KC - 1) + k;
    if (lt >= 0)
      acc = fmaf(cvt(xz[(size_t)(t - (KC - 1) + k) * (2 * DI) + d]), cw[d * KC + k], acc);
  }
  float s = acc / (1.f + expf(-acc));  // SiLU
  stv(&u[(size_t)t * DI + d], s);
}

// ---------------------------------------------------------------------------
// Selective scan, fused with skip (u*D) and gate (silu(z)).
// One chain = (b, d); 16 lanes per chain hold the DS=16 state elements.
// Block = 256 threads = 16 chains. Grid = B*DI/16 = 512 blocks.
// Writes y into the (now dead) x-half of xz, bf16.
// ---------------------------------------------------------------------------
__global__ __launch_bounds__(256) void scan_kernel(
    const bf16* __restrict__ delta, const bf16* __restrict__ u,
    const float* __restrict__ xdbl, bf16* __restrict__ xz,
    const float* __restrict__ A_log, const float* __restrict__ Dp) {
  int lane = threadIdx.x & 15;
  int chain = (blockIdx.x * 256 + threadIdx.x) >> 4;  // 0..B*DI-1
  int b = chain >> 11;                                // / DI
  int d = chain & (DI - 1);

  float Aj = -expf(A_log[d * DS + lane]);
  float Dd = Dp[d];
  float h = 0.f;

  for (int l = 0; l < LL; ++l) {
    int t = (b << 11) + l;
    float dlt = cvt(delta[(size_t)t * DI + d]);
    float ut = cvt(u[(size_t)t * DI + d]);
    float Bt = xdbl[(size_t)t * (DR + 2 * DS) + DR + lane];
    float Ct = xdbl[(size_t)t * (DR + 2 * DS) + DR + DS + lane];
    float dA = expf(dlt * Aj);
    h = fmaf(dA, h, dlt * ut * Bt);
    float yp = h * Ct;
    yp += __shfl_xor(yp, 1);
    yp += __shfl_xor(yp, 2);
    yp += __shfl_xor(yp, 4);
    yp += __shfl_xor(yp, 8);
    if (lane == 0) {
      float zt = cvt(xz[(size_t)t * (2 * DI) + DI + d]);
      float g = zt / (1.f + expf(-zt));
      stv(&xz[(size_t)t * (2 * DI) + d], (yp + ut * Dd) * g);  // y aliases x-half
    }
  }
}

// ---------------------------------------------------------------------------
extern "C" void kernel_launch(void* const* d_in, const int* in_sizes, int n_in,
                              void* d_out, int out_size, void* d_ws, size_t ws_size,
                              hipStream_t stream) {
  const float* hidden    = (const float*)d_in[0];
  const float* in_proj_w = (const float*)d_in[1];
  const float* conv_w    = (const float*)d_in[2];
  const float* conv_b    = (const float*)d_in[3];
  const float* x_proj_w  = (const float*)d_in[4];
  const float* dt_proj_w = (const float*)d_in[5];
  const float* dt_proj_b = (const float*)d_in[6];
  const float* A_log     = (const float*)d_in[7];
  const float* D_param   = (const float*)d_in[8];
  const float* out_proj_w= (const float*)d_in[9];
  float* out = (float*)d_out;

  // Workspace layout (bf16 intermediates; y aliases x-half of xz):
  //   xz:    TT x 4096 bf16   (64 MB)
  //   u:     TT x 2048 bf16   (32 MB)
  //   xdbl:  TT x 96   f32    ( 3 MB)
  //   delta: TT x 2048 bf16   (32 MB)
  size_t need = (size_t)TT * 4096 * sizeof(bf16) + (size_t)TT * DI * sizeof(bf16)
              + (size_t)TT * (DR + 2 * DS) * sizeof(float) + (size_t)TT * DI * sizeof(bf16);
  if (ws_size < need) return;  // diagnostic guard: clean fail instead of fault

  bf16* xz     = (bf16*)d_ws;                        // TT x 2*DI
  bf16* u      = xz + (size_t)TT * 2 * DI;           // TT x DI
  float* xdbl  = (float*)(u + (size_t)TT * DI);      // TT x 96
  bf16* delta  = (bf16*)(xdbl + (size_t)TT * (DR + 2 * DS));  // TT x DI

  dim3 blk(256);

  // 1) xz = hidden @ in_proj_w^T     (8192 x 4096, K=1024)
  gemm_nt<float, bf16, 0><<<dim3((2 * DI) / 64, TT / 64), blk, 0, stream>>>(
      hidden, DM, in_proj_w, nullptr, xz, 2 * DI, TT, 2 * DI, DM);

  // 2) u = silu(causal_conv(x) + cb)
  conv_silu<<<dim3(DI / 256, TT), blk, 0, stream>>>(xz, conv_w, conv_b, u);

  // 3) x_dbl = u @ x_proj_w^T        (8192 x 96, K=2048)
  gemm_nt<bf16, float, 0><<<dim3(2, TT / 64), blk, 0, stream>>>(
      u, DI, x_proj_w, nullptr, xdbl, DR + 2 * DS, TT, DR + 2 * DS, DI);

  // 4) delta = softplus(x_dbl[:, :64] @ dt_proj_w^T + dt_proj_b)  (8192 x 2048, K=64)
  gemm_nt<float, bf16, 1><<<dim3(DI / 64, TT / 64), blk, 0, stream>>>(
      xdbl, DR + 2 * DS, dt_proj_w, dt_proj_b, delta, DI, TT, DI, DR);

  // 5) selective scan + skip + gate -> y (into x-half of xz)
  scan_kernel<<<dim3((BB * DI) / 16), blk, 0, stream>>>(
      delta, u, xdbl, xz, A_log, D_param);

  // 6) out = y @ out_proj_w^T        (8192 x 1024, K=2048); y is x-half of xz, lda=4096
  gemm_nt<bf16, float, 0><<<dim3(DM / 64, TT / 64), blk, 0, stream>>>(
      xz, 2 * DI, out_proj_w, nullptr, out, DM, TT, DM, DI);
}

// Round 3
// 1338.042 us; speedup vs baseline: 3.3147x; 3.3147x over previous
//
#include <hip/hip_runtime.h>
#include <hip/hip_bf16.h>
#include <math.h>

// Problem constants
#define BB 4
#define LL 2048
#define DM 1024
#define DI 2048
#define DS 16
#define DR 64
#define KC 4
#define TT (BB * LL)   // 8192 tokens
#define NC 8           // scan chunks per sequence
#define CL (LL / NC)   // 256 steps per chunk

typedef __hip_bfloat16 bf16;
typedef short bf16x8 __attribute__((ext_vector_type(8)));
typedef short short8 __attribute__((ext_vector_type(8)));
typedef float f32x4 __attribute__((ext_vector_type(4)));
typedef float float4v __attribute__((ext_vector_type(4)));

__device__ __forceinline__ float cvt(float v) { return v; }
__device__ __forceinline__ float cvt(bf16 v) { return __bfloat162float(v); }
__device__ __forceinline__ void stv(float* p, float v) { *p = v; }
__device__ __forceinline__ void stv(bf16* p, float v) { *p = __float2bfloat16(v); }
__device__ __forceinline__ short f2bf(float f) {
  union { bf16 h; short s; } u_; u_.h = __float2bfloat16(f); return u_.s;
}

// ---------------------------------------------------------------------------
// MFMA GEMM: C[M,N] = A[M,K] * W[N,K]^T.  A: f32 or bf16 (converted to bf16
// during LDS staging), W: f32 (converted), C: f32 or bf16. fp32 accumulate.
// 128x128 tile, 4 waves (2x2 of 64x64), BK=32, mfma_f32_16x16x32_bf16.
// LDS rows padded to 40 shorts (80B stride -> conflict-light b128 reads).
// Dims must divide: M%128==0, N%128==0, K%32==0 (true for all uses here).
// ---------------------------------------------------------------------------
__device__ __forceinline__ void loadcvt16(const float* p, short* d) {
#pragma unroll
  for (int i = 0; i < 4; ++i) {
    float4v v = ((const float4v*)p)[i];
#pragma unroll
    for (int j = 0; j < 4; ++j) d[i * 4 + j] = f2bf(v[j]);
  }
}
__device__ __forceinline__ void loadcvt16(const bf16* p, short* d) {
  ((short8*)d)[0] = ((const short8*)p)[0];
  ((short8*)d)[1] = ((const short8*)p)[1];
}

template <typename TA, typename TC>
__global__ __launch_bounds__(256) void gemm_mfma(
    const TA* __restrict__ A, int lda,
    const float* __restrict__ W, int ldw,
    TC* __restrict__ C, int ldc, int Kd) {
  __shared__ short As[128 * 40];
  __shared__ short Bs[128 * 40];
  int tid = threadIdx.x;
  int bm = blockIdx.y * 128, bn = blockIdx.x * 128;

  // staging role: thread covers row r, 16-col half hh of the 128x32 tile
  int r = tid >> 1, hh = (tid & 1) * 16;
  const TA* ga = A + (size_t)(bm + r) * lda + hh;
  const float* gw = W + (size_t)(bn + r) * ldw + hh;

  // compute role
  int wave = tid >> 6, lane = tid & 63;
  int wm = (wave >> 1) * 64, wn = (wave & 1) * 64;
  int lr = lane & 15, kg = lane >> 4;

  f32x4 acc[4][4] = {};

  for (int k0 = 0; k0 < Kd; k0 += 32) {
    short abuf[16], wbuf[16];
    loadcvt16(ga + k0, abuf);   // issue global loads early
    loadcvt16(gw + k0, wbuf);
    __syncthreads();            // previous iter's LDS reads done
    ((short8*)&As[r * 40 + hh])[0] = ((short8*)abuf)[0];
    ((short8*)&As[r * 40 + hh])[1] = ((short8*)abuf)[1];
    ((short8*)&Bs[r * 40 + hh])[0] = ((short8*)wbuf)[0];
    ((short8*)&Bs[r * 40 + hh])[1] = ((short8*)wbuf)[1];
    __syncthreads();            // LDS tile visible

    bf16x8 af[4], bfr[4];
#pragma unroll
    for (int i = 0; i < 4; ++i)
      af[i] = *(const bf16x8*)&As[(wm + i * 16 + lr) * 40 + kg * 8];
#pragma unroll
    for (int j = 0; j < 4; ++j)
      bfr[j] = *(const bf16x8*)&Bs[(wn + j * 16 + lr) * 40 + kg * 8];
#pragma unroll
    for (int i = 0; i < 4; ++i)
#pragma unroll
      for (int j = 0; j < 4; ++j)
        acc[i][j] = __builtin_amdgcn_mfma_f32_16x16x32_bf16(af[i], bfr[j], acc[i][j], 0, 0, 0);
  }

  // epilogue: D row=(lane>>4)*4+reg, col=lane&15  [m89-verified]
#pragma unroll
  for (int i = 0; i < 4; ++i) {
    int row0 = bm + wm + i * 16 + kg * 4;
#pragma unroll
    for (int j = 0; j < 4; ++j) {
      int col = bn + wn + j * 16 + lr;
#pragma unroll
      for (int rr = 0; rr < 4; ++rr)
        stv(&C[(size_t)(row0 + rr) * ldc + col], acc[i][j][rr]);
    }
  }
}

// ---------------------------------------------------------------------------
// fp32 VALU GEMM (kept for the two small GEMMs): C = A * W^T (+softplus epi)
// ---------------------------------------------------------------------------
template <typename TA, typename TC, int EPI>
__global__ __launch_bounds__(256) void gemm_nt(
    const TA* __restrict__ A, int lda,
    const float* __restrict__ W,
    const float* __restrict__ bias,
    TC* __restrict__ C, int ldc,
    int M, int N, int Kd) {
  const int BM = 64, BN = 64, BK = 16;
  __shared__ float Asm[BK][BM + 1];
  __shared__ float Wsm[BK][BN + 1];

  int bn = blockIdx.x * BN;
  int bm = blockIdx.y * BM;
  int tid = threadIdx.x;
  int tx = tid & 15;
  int ty = tid >> 4;
  float acc[4][4] = {};

  for (int k0 = 0; k0 < Kd; k0 += BK) {
#pragma unroll
    for (int p = 0; p < 4; ++p) {
      int rr = (tid >> 4) + p * 16;
      int cc = tid & 15;
      int gr = bm + rr, gc = k0 + cc;
      Asm[cc][rr] = (gr < M && gc < Kd) ? cvt(A[(size_t)gr * lda + gc]) : 0.f;
      int wr = bn + rr;
      Wsm[cc][rr] = (wr < N && gc < Kd) ? W[(size_t)wr * Kd + gc] : 0.f;
    }
    __syncthreads();
#pragma unroll
    for (int kk = 0; kk < BK; ++kk) {
      float a[4], w[4];
#pragma unroll
      for (int i = 0; i < 4; ++i) a[i] = Asm[kk][ty * 4 + i];
#pragma unroll
      for (int j = 0; j < 4; ++j) w[j] = Wsm[kk][tx * 4 + j];
#pragma unroll
      for (int i = 0; i < 4; ++i)
#pragma unroll
        for (int j = 0; j < 4; ++j)
          acc[i][j] = fmaf(a[i], w[j], acc[i][j]);
    }
    __syncthreads();
  }

#pragma unroll
  for (int i = 0; i < 4; ++i) {
    int rr = bm + ty * 4 + i;
    if (rr >= M) continue;
#pragma unroll
    for (int j = 0; j < 4; ++j) {
      int cc = bn + tx * 4 + j;
      if (cc >= N) continue;
      float v = acc[i][j];
      if (EPI == 1) {
        v += bias[cc];
        v = (v > 20.f) ? v : log1pf(expf(v));
      }
      stv(&C[(size_t)rr * ldc + cc], v);
    }
  }
}

// ---------------------------------------------------------------------------
// Depthwise causal conv1d (K=4) + bias + SiLU.
// ---------------------------------------------------------------------------
__global__ __launch_bounds__(256) void conv_silu(
    const bf16* __restrict__ xz, const float* __restrict__ cw,
    const float* __restrict__ cb, bf16* __restrict__ u) {
  int d = blockIdx.x * 256 + threadIdx.x;
  int t = blockIdx.y;
  int l = t & (LL - 1);
  float acc = cb[d];
#pragma unroll
  for (int k = 0; k < KC; ++k) {
    int lt = l - (KC - 1) + k;
    if (lt >= 0)
      acc = fmaf(cvt(xz[(size_t)(t - (KC - 1) + k) * (2 * DI) + d]), cw[d * KC + k], acc);
  }
  float s = acc / (1.f + __expf(-acc));
  stv(&u[(size_t)t * DI + d], s);
}

// ---------------------------------------------------------------------------
// Chunked selective scan. State (hend/hin/sumd, 8.25MB f32) aliases into the
// dead x-half of xz (row t -> first 4096 bytes of xz row t; rows 0..2111).
// ---------------------------------------------------------------------------
__device__ __forceinline__ float* stslot(bf16* xz, int idx) {
  int t = idx >> 10, j = idx & 1023;
  return (float*)((char*)xz + (size_t)t * 8192) + j;
}
#define HEND_BASE 0
#define HIN_BASE  (8192 * NC * DS)            // 1048576
#define SUMD_BASE (2 * 8192 * NC * DS)        // 2097152

// Phase A: per-(chain,chunk) local scan from h=0; store end-state + sum(delta).
// task g: c = g>>13 (chunk), chain = g&8191; 16 tasks/block.
__global__ __launch_bounds__(256) void scan_local(
    const bf16* __restrict__ delta, const bf16* __restrict__ u,
    const float* __restrict__ xdbl, bf16* __restrict__ xz,
    const float* __restrict__ A_log) {
  int lane = threadIdx.x & 15;
  int g = blockIdx.x * 16 + (threadIdx.x >> 4);
  int c = g >> 13;
  int chain = g & 8191;
  int b = chain >> 11, d = chain & (DI - 1);
  float Aj = -__expf(A_log[d * DS + lane]);
  float h = 0.f, sd = 0.f;
  int t0 = b * LL + c * CL;
  for (int i = 0; i < CL; ++i) {
    int t = t0 + i;
    float dlt = cvt(delta[(size_t)t * DI + d]);
    float ut = cvt(u[(size_t)t * DI + d]);
    float Bt = xdbl[(size_t)t * (DR + 2 * DS) + DR + lane];
    h = fmaf(__expf(dlt * Aj), h, dlt * ut * Bt);
    sd += dlt;
  }
  *stslot(xz, HEND_BASE + (chain * NC + c) * DS + lane) = h;
  if (lane == 0) *stslot(xz, SUMD_BASE + chain * NC + c) = sd;
}

// Phase B: serial carry over the NC chunk summaries per chain.
__global__ __launch_bounds__(256) void scan_fix(
    bf16* __restrict__ xz, const float* __restrict__ A_log) {
  int lane = threadIdx.x & 15;
  int chain = blockIdx.x * 16 + (threadIdx.x >> 4);
  int d = chain & (DI - 1);
  float Aj = -__expf(A_log[d * DS + lane]);
  float carry = 0.f;
  for (int c = 0; c < NC; ++c) {
    *stslot(xz, HIN_BASE + (chain * NC + c) * DS + lane) = carry;
    float sd = *stslot(xz, SUMD_BASE + chain * NC + c);
    float he = *stslot(xz, HEND_BASE + (chain * NC + c) * DS + lane);
    carry = fmaf(__expf(Aj * sd), carry, he);
  }
}

// Phase C: re-run local scan with correct h_in; fuse y = (h.C + u*D)*silu(z);
// write y in-place into u (each element read-then-written by its owner).
__global__ __launch_bounds__(256) void scan_final(
    const bf16* __restrict__ delta, bf16* __restrict__ u,
    const float* __restrict__ xdbl, bf16* __restrict__ xz,
    const float* __restrict__ A_log, const float* __restrict__ Dp) {
  int lane = threadIdx.x & 15;
  int g = blockIdx.x * 16 + (threadIdx.x >> 4);
  int c = g >> 13;
  int chain = g & 8191;
  int b = chain >> 11, d = chain & (DI - 1);
  float Aj = -__expf(A_log[d * DS + lane]);
  float Dd = Dp[d];
  float h = *stslot(xz, HIN_BASE + (chain * NC + c) * DS + lane);
  int t0 = b * LL + c * CL;
  for (int i = 0; i < CL; ++i) {
    int t = t0 + i;
    float dlt = cvt(delta[(size_t)t * DI + d]);
    float ut = cvt(u[(size_t)t * DI + d]);
    float Bt = xdbl[(size_t)t * (DR + 2 * DS) + DR + lane];
    float Ct = xdbl[(size_t)t * (DR + 2 * DS) + DR + DS + lane];
    h = fmaf(__expf(dlt * Aj), h, dlt * ut * Bt);
    float yp = h * Ct;
    yp += __shfl_xor(yp, 1);
    yp += __shfl_xor(yp, 2);
    yp += __shfl_xor(yp, 4);
    yp += __shfl_xor(yp, 8);
    if (lane == 0) {
      float zt = cvt(xz[(size_t)t * (2 * DI) + DI + d]);
      float gte = zt / (1.f + __expf(-zt));
      stv(&u[(size_t)t * DI + d], (yp + ut * Dd) * gte);
    }
  }
}

// ---------------------------------------------------------------------------
extern "C" void kernel_launch(void* const* d_in, const int* in_sizes, int n_in,
                              void* d_out, int out_size, void* d_ws, size_t ws_size,
                              hipStream_t stream) {
  const float* hidden    = (const float*)d_in[0];
  const float* in_proj_w = (const float*)d_in[1];
  const float* conv_w    = (const float*)d_in[2];
  const float* conv_b    = (const float*)d_in[3];
  const float* x_proj_w  = (const float*)d_in[4];
  const float* dt_proj_w = (const float*)d_in[5];
  const float* dt_proj_b = (const float*)d_in[6];
  const float* A_log     = (const float*)d_in[7];
  const float* D_param   = (const float*)d_in[8];
  const float* out_proj_w= (const float*)d_in[9];
  float* out = (float*)d_out;

  // Workspace (131 MB, same proven footprint as round 2):
  //   xz 64MB bf16 | u 32MB bf16 | xdbl 3MB f32 | delta 32MB bf16
  size_t need = (size_t)TT * 4096 * sizeof(bf16) + (size_t)TT * DI * sizeof(bf16)
              + (size_t)TT * (DR + 2 * DS) * sizeof(float) + (size_t)TT * DI * sizeof(bf16);
  if (ws_size < need) return;

  bf16* xz     = (bf16*)d_ws;
  bf16* u      = xz + (size_t)TT * 2 * DI;
  float* xdbl  = (float*)(u + (size_t)TT * DI);
  bf16* delta  = (bf16*)(xdbl + (size_t)TT * (DR + 2 * DS));

  dim3 blk(256);

  // 1) xz = hidden @ in_proj_w^T   (MFMA, M=8192 N=4096 K=1024)
  gemm_mfma<float, bf16><<<dim3(4096 / 128, TT / 128), blk, 0, stream>>>(
      hidden, DM, in_proj_w, DM, xz, 2 * DI, DM);

  // 2) u = silu(causal_conv(x) + cb)
  conv_silu<<<dim3(DI / 256, TT), blk, 0, stream>>>(xz, conv_w, conv_b, u);

  // 3) x_dbl = u @ x_proj_w^T      (fp32, N=96 K=2048)
  gemm_nt<bf16, float, 0><<<dim3(2, TT / 64), blk, 0, stream>>>(
      u, DI, x_proj_w, nullptr, xdbl, DR + 2 * DS, TT, DR + 2 * DS, DI);

  // 4) delta = softplus(x_dbl[:, :64] @ dt_proj_w^T + b)  (fp32, N=2048 K=64)
  gemm_nt<float, bf16, 1><<<dim3(DI / 64, TT / 64), blk, 0, stream>>>(
      xdbl, DR + 2 * DS, dt_proj_w, dt_proj_b, delta, DI, TT, DI, DR);

  // 5) chunked selective scan; y -> in-place into u
  scan_local<<<dim3(8192 * NC / 16), blk, 0, stream>>>(delta, u, xdbl, xz, A_log);
  scan_fix<<<dim3(8192 / 16), blk, 0, stream>>>(xz, A_log);
  scan_final<<<dim3(8192 * NC / 16), blk, 0, stream>>>(delta, u, xdbl, xz, A_log, D_param);

  // 6) out = y @ out_proj_w^T      (MFMA, M=8192 N=1024 K=2048)
  gemm_mfma<bf16, float><<<dim3(DM / 128, TT / 128), blk, 0, stream>>>(
      u, DI, out_proj_w, DI, out, DM, DI);
}

// Round 4
// 953.301 us; speedup vs baseline: 4.6525x; 1.4036x over previous
//
#include <hip/hip_runtime.h>
#include <hip/hip_bf16.h>
#include <math.h>

// Problem constants
#define BB 4
#define LL 2048
#define DM 1024
#define DI 2048
#define DS 16
#define DR 64
#define KC 4
#define TT (BB * LL)   // 8192 tokens
#define NC 32          // scan chunks per sequence
#define CL (LL / NC)   // 64 steps per chunk

typedef __hip_bfloat16 bf16;
typedef short bf16x8 __attribute__((ext_vector_type(8)));
typedef short short8 __attribute__((ext_vector_type(8)));
typedef float f32x4 __attribute__((ext_vector_type(4)));
typedef float float4v __attribute__((ext_vector_type(4)));

__device__ __forceinline__ float cvt(float v) { return v; }
__device__ __forceinline__ float cvt(bf16 v) { return __bfloat162float(v); }
__device__ __forceinline__ void stv(float* p, float v) { *p = v; }
__device__ __forceinline__ void stv(bf16* p, float v) { *p = __float2bfloat16(v); }
__device__ __forceinline__ short f2bf(float f) {
  union { bf16 h; short s; } u_; u_.h = __float2bfloat16(f); return u_.s;
}

// ---------------------------------------------------------------------------
// MFMA GEMM: C[M,N] = A[M,K] * W[N,K]^T.  (unchanged from round 3)
// 128x128 tile, 4 waves (2x2 of 64x64), BK=32, mfma_f32_16x16x32_bf16.
// ---------------------------------------------------------------------------
__device__ __forceinline__ void loadcvt16(const float* p, short* d) {
#pragma unroll
  for (int i = 0; i < 4; ++i) {
    float4v v = ((const float4v*)p)[i];
#pragma unroll
    for (int j = 0; j < 4; ++j) d[i * 4 + j] = f2bf(v[j]);
  }
}
__device__ __forceinline__ void loadcvt16(const bf16* p, short* d) {
  ((short8*)d)[0] = ((const short8*)p)[0];
  ((short8*)d)[1] = ((const short8*)p)[1];
}

template <typename TA, typename TC>
__global__ __launch_bounds__(256) void gemm_mfma(
    const TA* __restrict__ A, int lda,
    const float* __restrict__ W, int ldw,
    TC* __restrict__ C, int ldc, int Kd) {
  __shared__ short As[128 * 40];
  __shared__ short Bs[128 * 40];
  int tid = threadIdx.x;
  int bm = blockIdx.y * 128, bn = blockIdx.x * 128;

  int r = tid >> 1, hh = (tid & 1) * 16;
  const TA* ga = A + (size_t)(bm + r) * lda + hh;
  const float* gw = W + (size_t)(bn + r) * ldw + hh;

  int wave = tid >> 6, lane = tid & 63;
  int wm = (wave >> 1) * 64, wn = (wave & 1) * 64;
  int lr = lane & 15, kg = lane >> 4;

  f32x4 acc[4][4] = {};

  for (int k0 = 0; k0 < Kd; k0 += 32) {
    short abuf[16], wbuf[16];
    loadcvt16(ga + k0, abuf);
    loadcvt16(gw + k0, wbuf);
    __syncthreads();
    ((short8*)&As[r * 40 + hh])[0] = ((short8*)abuf)[0];
    ((short8*)&As[r * 40 + hh])[1] = ((short8*)abuf)[1];
    ((short8*)&Bs[r * 40 + hh])[0] = ((short8*)wbuf)[0];
    ((short8*)&Bs[r * 40 + hh])[1] = ((short8*)wbuf)[1];
    __syncthreads();

    bf16x8 af[4], bfr[4];
#pragma unroll
    for (int i = 0; i < 4; ++i)
      af[i] = *(const bf16x8*)&As[(wm + i * 16 + lr) * 40 + kg * 8];
#pragma unroll
    for (int j = 0; j < 4; ++j)
      bfr[j] = *(const bf16x8*)&Bs[(wn + j * 16 + lr) * 40 + kg * 8];
#pragma unroll
    for (int i = 0; i < 4; ++i)
#pragma unroll
      for (int j = 0; j < 4; ++j)
        acc[i][j] = __builtin_amdgcn_mfma_f32_16x16x32_bf16(af[i], bfr[j], acc[i][j], 0, 0, 0);
  }

#pragma unroll
  for (int i = 0; i < 4; ++i) {
    int row0 = bm + wm + i * 16 + kg * 4;
#pragma unroll
    for (int j = 0; j < 4; ++j) {
      int col = bn + wn + j * 16 + lr;
#pragma unroll
      for (int rr = 0; rr < 4; ++rr)
        stv(&C[(size_t)(row0 + rr) * ldc + col], acc[i][j][rr]);
    }
  }
}

// ---------------------------------------------------------------------------
// fp32 VALU GEMM (two small GEMMs): C = A * W^T (+softplus epi)
// ---------------------------------------------------------------------------
template <typename TA, typename TC, int EPI>
__global__ __launch_bounds__(256) void gemm_nt(
    const TA* __restrict__ A, int lda,
    const float* __restrict__ W,
    const float* __restrict__ bias,
    TC* __restrict__ C, int ldc,
    int M, int N, int Kd) {
  const int BM = 64, BN = 64, BK = 16;
  __shared__ float Asm[BK][BM + 1];
  __shared__ float Wsm[BK][BN + 1];

  int bn = blockIdx.x * BN;
  int bm = blockIdx.y * BM;
  int tid = threadIdx.x;
  int tx = tid & 15;
  int ty = tid >> 4;
  float acc[4][4] = {};

  for (int k0 = 0; k0 < Kd; k0 += BK) {
#pragma unroll
    for (int p = 0; p < 4; ++p) {
      int rr = (tid >> 4) + p * 16;
      int cc = tid & 15;
      int gr = bm + rr, gc = k0 + cc;
      Asm[cc][rr] = (gr < M && gc < Kd) ? cvt(A[(size_t)gr * lda + gc]) : 0.f;
      int wr = bn + rr;
      Wsm[cc][rr] = (wr < N && gc < Kd) ? W[(size_t)wr * Kd + gc] : 0.f;
    }
    __syncthreads();
#pragma unroll
    for (int kk = 0; kk < BK; ++kk) {
      float a[4], w[4];
#pragma unroll
      for (int i = 0; i < 4; ++i) a[i] = Asm[kk][ty * 4 + i];
#pragma unroll
      for (int j = 0; j < 4; ++j) w[j] = Wsm[kk][tx * 4 + j];
#pragma unroll
      for (int i = 0; i < 4; ++i)
#pragma unroll
        for (int j = 0; j < 4; ++j)
          acc[i][j] = fmaf(a[i], w[j], acc[i][j]);
    }
    __syncthreads();
  }

#pragma unroll
  for (int i = 0; i < 4; ++i) {
    int rr = bm + ty * 4 + i;
    if (rr >= M) continue;
#pragma unroll
    for (int j = 0; j < 4; ++j) {
      int cc = bn + tx * 4 + j;
      if (cc >= N) continue;
      float v = acc[i][j];
      if (EPI == 1) {
        v += bias[cc];
        v = (v > 20.f) ? v : log1pf(expf(v));
      }
      stv(&C[(size_t)rr * ldc + cc], v);
    }
  }
}

// ---------------------------------------------------------------------------
// Depthwise causal conv1d (K=4) + bias + SiLU.
// ---------------------------------------------------------------------------
__global__ __launch_bounds__(256) void conv_silu(
    const bf16* __restrict__ xz, const float* __restrict__ cw,
    const float* __restrict__ cb, bf16* __restrict__ u) {
  int d = blockIdx.x * 256 + threadIdx.x;
  int t = blockIdx.y;
  int l = t & (LL - 1);
  float acc = cb[d];
#pragma unroll
  for (int k = 0; k < KC; ++k) {
    int lt = l - (KC - 1) + k;
    if (lt >= 0)
      acc = fmaf(cvt(xz[(size_t)(t - (KC - 1) + k) * (2 * DI) + d]), cw[d * KC + k], acc);
  }
  float s = acc / (1.f + __expf(-acc));
  stv(&u[(size_t)t * DI + d], s);
}

// ---------------------------------------------------------------------------
// Chunked selective scan, THREAD-PER-CHAIN: one thread owns all 16 states in
// registers. B/C are wave-broadcast float4 loads; delta/u/z coalesced scalars;
// h.C is an in-register dot (no shuffles); gate on all lanes.
// Scan state (hend 16MB + sumd 1MB, hin aliases hend in-place) lives in the
// dead x-half of xz (rows t, first 4096 bytes each).
// ---------------------------------------------------------------------------
__device__ __forceinline__ float* stslot(bf16* xz, int idx) {
  int t = idx >> 10, j = idx & 1023;
  return (float*)((char*)xz + (size_t)t * 8192) + j;
}
#define SUMD_BASE (8192 * NC * DS)   // 4194304 floats -> rows 4096..4351

// Phase A: per-(chain,chunk) local scan from h=0; store end-state + sum(delta).
// g: d = g & 2047 (fastest, coalesced), b = (g>>11)&3, c = g>>13.
__global__ __launch_bounds__(256) void scan_local(
    const bf16* __restrict__ delta, const bf16* __restrict__ u,
    const float* __restrict__ xdbl, bf16* __restrict__ xz,
    const float* __restrict__ A_log) {
  int g = blockIdx.x * 256 + threadIdx.x;
  int d = g & (DI - 1);
  int b = (g >> 11) & (BB - 1);
  int c = g >> 13;
  int chain = (b << 11) | d;

  float Aj[DS];
  const float4v* Ap = (const float4v*)&A_log[d * DS];
#pragma unroll
  for (int i = 0; i < 4; ++i) {
    float4v v = Ap[i];
#pragma unroll
    for (int j = 0; j < 4; ++j) Aj[i * 4 + j] = -__expf(v[j]);
  }

  float h[DS];
#pragma unroll
  for (int s = 0; s < DS; ++s) h[s] = 0.f;
  float sd = 0.f;
  int t0 = b * LL + c * CL;

  for (int i = 0; i < CL; ++i) {
    int t = t0 + i;
    float dlt = cvt(delta[(size_t)t * DI + d]);
    float ut = cvt(u[(size_t)t * DI + d]);
    const float4v* Bp = (const float4v*)&xdbl[(size_t)t * (DR + 2 * DS) + DR];
    float Bv[DS];
#pragma unroll
    for (int q = 0; q < 4; ++q) {
      float4v v = Bp[q];
#pragma unroll
      for (int j = 0; j < 4; ++j) Bv[q * 4 + j] = v[j];
    }
    float du = dlt * ut;
    sd += dlt;
#pragma unroll
    for (int s = 0; s < DS; ++s)
      h[s] = fmaf(__expf(dlt * Aj[s]), h[s], du * Bv[s]);
  }

  float* hp = stslot(xz, (chain * NC + c) * DS);
  float4v* hv = (float4v*)hp;
#pragma unroll
  for (int q = 0; q < 4; ++q) {
    float4v v;
#pragma unroll
    for (int j = 0; j < 4; ++j) v[j] = h[q * 4 + j];
    hv[q] = v;
  }
  *stslot(xz, SUMD_BASE + chain * NC + c) = sd;
}

// Phase B: serial carry over NC chunk summaries per chain; hin overwrites
// hend in place (lane s = state s, 16 lanes per chain).
__global__ __launch_bounds__(256) void scan_fix(
    bf16* __restrict__ xz, const float* __restrict__ A_log) {
  int lane = threadIdx.x & 15;
  int chain = blockIdx.x * 16 + (threadIdx.x >> 4);
  int d = chain & (DI - 1);
  float Aj = -__expf(A_log[d * DS + lane]);
  float carry = 0.f;
  for (int c = 0; c < NC; ++c) {
    float* hp = stslot(xz, (chain * NC + c) * DS + lane);
    float sd = *stslot(xz, SUMD_BASE + chain * NC + c);
    float he = *hp;
    *hp = carry;
    carry = fmaf(__expf(Aj * sd), carry, he);
  }
}

// Phase C: re-run local scan with correct h_in; fuse y=(h.C + u*D)*silu(z);
// y written in-place into u.
__global__ __launch_bounds__(256) void scan_final(
    const bf16* __restrict__ delta, bf16* __restrict__ u,
    const float* __restrict__ xdbl, bf16* __restrict__ xz,
    const float* __restrict__ A_log, const float* __restrict__ Dp) {
  int g = blockIdx.x * 256 + threadIdx.x;
  int d = g & (DI - 1);
  int b = (g >> 11) & (BB - 1);
  int c = g >> 13;
  int chain = (b << 11) | d;

  float Aj[DS];
  const float4v* Ap = (const float4v*)&A_log[d * DS];
#pragma unroll
  for (int i = 0; i < 4; ++i) {
    float4v v = Ap[i];
#pragma unroll
    for (int j = 0; j < 4; ++j) Aj[i * 4 + j] = -__expf(v[j]);
  }
  float Dd = Dp[d];

  float h[DS];
  const float4v* hv = (const float4v*)stslot(xz, (chain * NC + c) * DS);
#pragma unroll
  for (int q = 0; q < 4; ++q) {
    float4v v = hv[q];
#pragma unroll
    for (int j = 0; j < 4; ++j) h[q * 4 + j] = v[j];
  }

  int t0 = b * LL + c * CL;
  for (int i = 0; i < CL; ++i) {
    int t = t0 + i;
    float dlt = cvt(delta[(size_t)t * DI + d]);
    float ut = cvt(u[(size_t)t * DI + d]);
    const float4v* Bp = (const float4v*)&xdbl[(size_t)t * (DR + 2 * DS) + DR];
    float BC[2 * DS];
#pragma unroll
    for (int q = 0; q < 8; ++q) {
      float4v v = Bp[q];
#pragma unroll
      for (int j = 0; j < 4; ++j) BC[q * 4 + j] = v[j];
    }
    float du = dlt * ut;
    float yp = 0.f;
#pragma unroll
    for (int s = 0; s < DS; ++s) {
      h[s] = fmaf(__expf(dlt * Aj[s]), h[s], du * BC[s]);
      yp = fmaf(h[s], BC[DS + s], yp);
    }
    float zt = cvt(xz[(size_t)t * (2 * DI) + DI + d]);
    float gte = zt / (1.f + __expf(-zt));
    stv(&u[(size_t)t * DI + d], (yp + ut * Dd) * gte);
  }
}

// ---------------------------------------------------------------------------
extern "C" void kernel_launch(void* const* d_in, const int* in_sizes, int n_in,
                              void* d_out, int out_size, void* d_ws, size_t ws_size,
                              hipStream_t stream) {
  const float* hidden    = (const float*)d_in[0];
  const float* in_proj_w = (const float*)d_in[1];
  const float* conv_w    = (const float*)d_in[2];
  const float* conv_b    = (const float*)d_in[3];
  const float* x_proj_w  = (const float*)d_in[4];
  const float* dt_proj_w = (const float*)d_in[5];
  const float* dt_proj_b = (const float*)d_in[6];
  const float* A_log     = (const float*)d_in[7];
  const float* D_param   = (const float*)d_in[8];
  const float* out_proj_w= (const float*)d_in[9];
  float* out = (float*)d_out;

  // Workspace (131 MB, proven):
  //   xz 64MB bf16 | u 32MB bf16 | xdbl 3MB f32 | delta 32MB bf16
  size_t need = (size_t)TT * 4096 * sizeof(bf16) + (size_t)TT * DI * sizeof(bf16)
              + (size_t)TT * (DR + 2 * DS) * sizeof(float) + (size_t)TT * DI * sizeof(bf16);
  if (ws_size < need) return;

  bf16* xz     = (bf16*)d_ws;
  bf16* u      = xz + (size_t)TT * 2 * DI;
  float* xdbl  = (float*)(u + (size_t)TT * DI);
  bf16* delta  = (bf16*)(xdbl + (size_t)TT * (DR + 2 * DS));

  dim3 blk(256);

  // 1) xz = hidden @ in_proj_w^T   (MFMA, M=8192 N=4096 K=1024)
  gemm_mfma<float, bf16><<<dim3(4096 / 128, TT / 128), blk, 0, stream>>>(
      hidden, DM, in_proj_w, DM, xz, 2 * DI, DM);

  // 2) u = silu(causal_conv(x) + cb)
  conv_silu<<<dim3(DI / 256, TT), blk, 0, stream>>>(xz, conv_w, conv_b, u);

  // 3) x_dbl = u @ x_proj_w^T      (fp32, N=96 K=2048)
  gemm_nt<bf16, float, 0><<<dim3(2, TT / 64), blk, 0, stream>>>(
      u, DI, x_proj_w, nullptr, xdbl, DR + 2 * DS, TT, DR + 2 * DS, DI);

  // 4) delta = softplus(x_dbl[:, :64] @ dt_proj_w^T + b)  (fp32, N=2048 K=64)
  gemm_nt<float, bf16, 1><<<dim3(DI / 64, TT / 64), blk, 0, stream>>>(
      xdbl, DR + 2 * DS, dt_proj_w, dt_proj_b, delta, DI, TT, DI, DR);

  // 5) chunked selective scan (thread-per-chain); y -> in-place into u
  scan_local<<<dim3(8192 * NC / 256), blk, 0, stream>>>(delta, u, xdbl, xz, A_log);
  scan_fix<<<dim3(8192 / 16), blk, 0, stream>>>(xz, A_log);
  scan_final<<<dim3(8192 * NC / 256), blk, 0, stream>>>(delta, u, xdbl, xz, A_log, D_param);

  // 6) out = y @ out_proj_w^T      (MFMA, M=8192 N=1024 K=2048)
  gemm_mfma<bf16, float><<<dim3(DM / 128, TT / 128), blk, 0, stream>>>(
      u, DI, out_proj_w, DI, out, DM, DI);
}

// Round 6
// 609.147 us; speedup vs baseline: 7.2810x; 1.5650x over previous
//
#include <hip/hip_runtime.h>
#include <hip/hip_bf16.h>
#include <math.h>

// Problem constants
#define BB 4
#define LL 2048
#define DM 1024
#define DI 2048
#define DS 16
#define DR 64
#define KC 4
#define TT (BB * LL)   // 8192 tokens
#define NC 32          // scan chunks per sequence
#define CL (LL / NC)   // 64 steps per chunk
#define SK 8           // x_proj split-K factor

typedef __hip_bfloat16 bf16;
typedef short bf16x8 __attribute__((ext_vector_type(8)));
typedef short short8 __attribute__((ext_vector_type(8)));
typedef float f32x4 __attribute__((ext_vector_type(4)));
typedef float float4v __attribute__((ext_vector_type(4)));

__device__ __forceinline__ float cvt(float v) { return v; }
__device__ __forceinline__ float cvt(bf16 v) { return __bfloat162float(v); }
__device__ __forceinline__ float bf2f(short s) {
  union { short s; bf16 h; } c; c.s = s; return __bfloat162float(c.h);
}
__device__ __forceinline__ void stv(float* p, float v) { *p = v; }
__device__ __forceinline__ void stv(bf16* p, float v) { *p = __float2bfloat16(v); }
__device__ __forceinline__ short f2bf(float f) {
  union { bf16 h; short s; } u_; u_.h = __float2bfloat16(f); return u_.s;
}

// ---------------------------------------------------------------------------
// MFMA GEMM: C[M,N] = A[M,K] * W[N,K]^T (+ optional bias+softplus epilogue).
// 128x128 tile, 4 waves (2x2 of 64x64), BK=32, mfma_f32_16x16x32_bf16.
// A: f32 or bf16 (converted during reg-staging), W: f32 (converted).
// ---------------------------------------------------------------------------
__device__ __forceinline__ void loadcvt16(const float* p, short* d) {
#pragma unroll
  for (int i = 0; i < 4; ++i) {
    float4v v = ((const float4v*)p)[i];
#pragma unroll
    for (int j = 0; j < 4; ++j) d[i * 4 + j] = f2bf(v[j]);
  }
}
__device__ __forceinline__ void loadcvt16(const bf16* p, short* d) {
  ((short8*)d)[0] = ((const short8*)p)[0];
  ((short8*)d)[1] = ((const short8*)p)[1];
}

template <typename TA, typename TC, int EPI>
__global__ __launch_bounds__(256) void gemm_mfma(
    const TA* __restrict__ A, int lda,
    const float* __restrict__ W, int ldw,
    const float* __restrict__ bias,
    TC* __restrict__ C, int ldc, int Kd) {
  __shared__ short As[128 * 40];
  __shared__ short Bs[128 * 40];
  int tid = threadIdx.x;
  int bm = blockIdx.y * 128, bn = blockIdx.x * 128;

  int r = tid >> 1, hh = (tid & 1) * 16;
  const TA* ga = A + (size_t)(bm + r) * lda + hh;
  const float* gw = W + (size_t)(bn + r) * ldw + hh;

  int wave = tid >> 6, lane = tid & 63;
  int wm = (wave >> 1) * 64, wn = (wave & 1) * 64;
  int lr = lane & 15, kg = lane >> 4;

  f32x4 acc[4][4] = {};

  for (int k0 = 0; k0 < Kd; k0 += 32) {
    short abuf[16], wbuf[16];
    loadcvt16(ga + k0, abuf);
    loadcvt16(gw + k0, wbuf);
    __syncthreads();
    ((short8*)&As[r * 40 + hh])[0] = ((short8*)abuf)[0];
    ((short8*)&As[r * 40 + hh])[1] = ((short8*)abuf)[1];
    ((short8*)&Bs[r * 40 + hh])[0] = ((short8*)wbuf)[0];
    ((short8*)&Bs[r * 40 + hh])[1] = ((short8*)wbuf)[1];
    __syncthreads();

    bf16x8 af[4], bfr[4];
#pragma unroll
    for (int i = 0; i < 4; ++i)
      af[i] = *(const bf16x8*)&As[(wm + i * 16 + lr) * 40 + kg * 8];
#pragma unroll
    for (int j = 0; j < 4; ++j)
      bfr[j] = *(const bf16x8*)&Bs[(wn + j * 16 + lr) * 40 + kg * 8];
#pragma unroll
    for (int i = 0; i < 4; ++i)
#pragma unroll
      for (int j = 0; j < 4; ++j)
        acc[i][j] = __builtin_amdgcn_mfma_f32_16x16x32_bf16(af[i], bfr[j], acc[i][j], 0, 0, 0);
  }

#pragma unroll
  for (int i = 0; i < 4; ++i) {
    int row0 = bm + wm + i * 16 + kg * 4;
#pragma unroll
    for (int j = 0; j < 4; ++j) {
      int col = bn + wn + j * 16 + lr;
#pragma unroll
      for (int rr = 0; rr < 4; ++rr) {
        float v = acc[i][j][rr];
        if (EPI == 1) {
          v += bias[col];
          v = (v > 20.f) ? v : log1pf(expf(v));
        }
        stv(&C[(size_t)(row0 + rr) * ldc + col], v);
      }
    }
  }
}

// ---------------------------------------------------------------------------
// Scan-state / split-K partial aliasing into the dead x-half of xz:
// float slot idx -> row t = idx>>10 (first 4096 B of each 8192 B xz row).
// Partials (x_proj, 24 MB, rows 0..6143) are dead before scan state
// (rows 0..4351) is written.
// ---------------------------------------------------------------------------
__device__ __forceinline__ float* stslot(bf16* xz, int idx) {
  int t = idx >> 10, j = idx & 1023;
  return (float*)((char*)xz + (size_t)t * 8192) + j;
}
#define SUMD_BASE (8192 * NC * DS)   // floats; rows 4096..4351

// ---------------------------------------------------------------------------
// x_proj split-K: xdbl_partial[sk] = u[:,kslice] @ x_proj_w[:,kslice]^T
// BM=128 x N=96 per block, SK=8 K-slices of 256. 4 waves, each 32 rows x 96.
// ---------------------------------------------------------------------------
__global__ __launch_bounds__(256) void xproj_splitk(
    const bf16* __restrict__ u, const float* __restrict__ W,
    bf16* __restrict__ xz) {
  __shared__ short As[128 * 40];
  __shared__ short Bs[96 * 40];
  int tid = threadIdx.x;
  int bm = blockIdx.x * 128;
  int sk = blockIdx.y;
  int kb = sk * (DI / SK);          // 256-wide K slice

  int r = tid >> 1, hh = (tid & 1) * 16;
  const bf16* ga = u + (size_t)(bm + r) * DI + kb + hh;
  const float* gw = W + (size_t)r * DI + kb + hh;  // valid for r<96

  int wave = tid >> 6, lane = tid & 63;
  int wm = wave * 32;
  int lr = lane & 15, kg = lane >> 4;

  f32x4 acc[2][6] = {};

  for (int k0 = 0; k0 < DI / SK; k0 += 32) {
    short abuf[16], wbuf[16];
    loadcvt16(ga + k0, abuf);
    if (r < 96) loadcvt16(gw + k0, wbuf);
    __syncthreads();
    ((short8*)&As[r * 40 + hh])[0] = ((short8*)abuf)[0];
    ((short8*)&As[r * 40 + hh])[1] = ((short8*)abuf)[1];
    if (r < 96) {
      ((short8*)&Bs[r * 40 + hh])[0] = ((short8*)wbuf)[0];
      ((short8*)&Bs[r * 40 + hh])[1] = ((short8*)wbuf)[1];
    }
    __syncthreads();

    bf16x8 af[2], bfr[6];
#pragma unroll
    for (int i = 0; i < 2; ++i)
      af[i] = *(const bf16x8*)&As[(wm + i * 16 + lr) * 40 + kg * 8];
#pragma unroll
    for (int j = 0; j < 6; ++j)
      bfr[j] = *(const bf16x8*)&Bs[(j * 16 + lr) * 40 + kg * 8];
#pragma unroll
    for (int i = 0; i < 2; ++i)
#pragma unroll
      for (int j = 0; j < 6; ++j)
        acc[i][j] = __builtin_amdgcn_mfma_f32_16x16x32_bf16(af[i], bfr[j], acc[i][j], 0, 0, 0);
  }

#pragma unroll
  for (int i = 0; i < 2; ++i) {
#pragma unroll
    for (int j = 0; j < 6; ++j) {
      int col = j * 16 + lr;
#pragma unroll
      for (int rr = 0; rr < 4; ++rr) {
        int row = bm + wm + i * 16 + kg * 4 + rr;
        *stslot(xz, (sk * 8192 + row) * 96 + col) = acc[i][j][rr];
      }
    }
  }
}

// Reduce SK partials -> xdbl (f32).
__global__ __launch_bounds__(256) void xproj_reduce(
    bf16* __restrict__ xz, float* __restrict__ xdbl) {
  int gid = blockIdx.x * 256 + threadIdx.x;  // 0..786431
  float s = 0.f;
#pragma unroll
  for (int sk = 0; sk < SK; ++sk)
    s += *stslot(xz, sk * (8192 * 96) + gid);
  xdbl[gid] = s;
}

// ---------------------------------------------------------------------------
// Depthwise causal conv1d (K=4) + bias + SiLU — vectorized, 8 d's per thread.
// ---------------------------------------------------------------------------
__global__ __launch_bounds__(256) void conv_silu(
    const bf16* __restrict__ xz, const float* __restrict__ cw,
    const float* __restrict__ cb, bf16* __restrict__ u) {
  int t = blockIdx.x;
  int d0 = threadIdx.x * 8;
  int l = t & (LL - 1);

  float acc[8];
  float4v c0 = *(const float4v*)&cb[d0];
  float4v c1 = *(const float4v*)&cb[d0 + 4];
#pragma unroll
  for (int j = 0; j < 4; ++j) { acc[j] = c0[j]; acc[4 + j] = c1[j]; }

  float wv[32];
  const float4v* wp = (const float4v*)&cw[d0 * 4];
#pragma unroll
  for (int q = 0; q < 8; ++q) {
    float4v v = wp[q];
#pragma unroll
    for (int j = 0; j < 4; ++j) wv[q * 4 + j] = v[j];
  }

#pragma unroll
  for (int k = 0; k < KC; ++k) {
    int lt = l - (KC - 1) + k;
    if (lt >= 0) {
      short8 xv = *(const short8*)&xz[(size_t)(t - (KC - 1) + k) * (2 * DI) + d0];
#pragma unroll
      for (int q = 0; q < 8; ++q)
        acc[q] = fmaf(bf2f(xv[q]), wv[q * 4 + k], acc[q]);
    }
  }

  short8 ov;
#pragma unroll
  for (int q = 0; q < 8; ++q) {
    float s = acc[q] / (1.f + __expf(-acc[q]));
    ov[q] = f2bf(s);
  }
  *(short8*)&u[(size_t)t * DI + d0] = ov;
}

// ---------------------------------------------------------------------------
// Chunked selective scan, thread-per-chain (16 states in registers).
// ---------------------------------------------------------------------------
__global__ __launch_bounds__(256) void scan_local(
    const bf16* __restrict__ delta, const bf16* __restrict__ u,
    const float* __restrict__ xdbl, bf16* __restrict__ xz,
    const float* __restrict__ A_log) {
  int g = blockIdx.x * 256 + threadIdx.x;
  int d = g & (DI - 1);
  int b = (g >> 11) & (BB - 1);
  int c = g >> 13;
  int chain = (b << 11) | d;

  float Aj[DS];
  const float4v* Ap = (const float4v*)&A_log[d * DS];
#pragma unroll
  for (int i = 0; i < 4; ++i) {
    float4v v = Ap[i];
#pragma unroll
    for (int j = 0; j < 4; ++j) Aj[i * 4 + j] = -__expf(v[j]);
  }

  float h[DS];
#pragma unroll
  for (int s = 0; s < DS; ++s) h[s] = 0.f;
  float sd = 0.f;
  int t0 = b * LL + c * CL;

  for (int i = 0; i < CL; ++i) {
    int t = t0 + i;
    float dlt = cvt(delta[(size_t)t * DI + d]);
    float ut = cvt(u[(size_t)t * DI + d]);
    const float4v* Bp = (const float4v*)&xdbl[(size_t)t * (DR + 2 * DS) + DR];
    float Bv[DS];
#pragma unroll
    for (int q = 0; q < 4; ++q) {
      float4v v = Bp[q];
#pragma unroll
      for (int j = 0; j < 4; ++j) Bv[q * 4 + j] = v[j];
    }
    float du = dlt * ut;
    sd += dlt;
#pragma unroll
    for (int s = 0; s < DS; ++s)
      h[s] = fmaf(__expf(dlt * Aj[s]), h[s], du * Bv[s]);
  }

  float4v* hv = (float4v*)stslot(xz, (chain * NC + c) * DS);
#pragma unroll
  for (int q = 0; q < 4; ++q) {
    float4v v;
#pragma unroll
    for (int j = 0; j < 4; ++j) v[j] = h[q * 4 + j];
    hv[q] = v;
  }
  *stslot(xz, SUMD_BASE + chain * NC + c) = sd;
}

__global__ __launch_bounds__(256) void scan_fix(
    bf16* __restrict__ xz, const float* __restrict__ A_log) {
  int lane = threadIdx.x & 15;
  int chain = blockIdx.x * 16 + (threadIdx.x >> 4);
  int d = chain & (DI - 1);
  float Aj = -__expf(A_log[d * DS + lane]);
  float carry = 0.f;
  for (int c = 0; c < NC; ++c) {
    float* hp = stslot(xz, (chain * NC + c) * DS + lane);
    float sd = *stslot(xz, SUMD_BASE + chain * NC + c);
    float he = *hp;
    *hp = carry;
    carry = fmaf(__expf(Aj * sd), carry, he);
  }
}

__global__ __launch_bounds__(256) void scan_final(
    const bf16* __restrict__ delta, bf16* __restrict__ u,
    const float* __restrict__ xdbl, bf16* __restrict__ xz,
    const float* __restrict__ A_log, const float* __restrict__ Dp) {
  int g = blockIdx.x * 256 + threadIdx.x;
  int d = g & (DI - 1);
  int b = (g >> 11) & (BB - 1);
  int c = g >> 13;
  int chain = (b << 11) | d;

  float Aj[DS];
  const float4v* Ap = (const float4v*)&A_log[d * DS];
#pragma unroll
  for (int i = 0; i < 4; ++i) {
    float4v v = Ap[i];
#pragma unroll
    for (int j = 0; j < 4; ++j) Aj[i * 4 + j] = -__expf(v[j]);
  }
  float Dd = Dp[d];

  float h[DS];
  const float4v* hv = (const float4v*)stslot(xz, (chain * NC + c) * DS);
#pragma unroll
  for (int q = 0; q < 4; ++q) {
    float4v v = hv[q];
#pragma unroll
    for (int j = 0; j < 4; ++j) h[q * 4 + j] = v[j];
  }

  int t0 = b * LL + c * CL;
  for (int i = 0; i < CL; ++i) {
    int t = t0 + i;
    float dlt = cvt(delta[(size_t)t * DI + d]);
    float ut = cvt(u[(size_t)t * DI + d]);
    const float4v* Bp = (const float4v*)&xdbl[(size_t)t * (DR + 2 * DS) + DR];
    float BC[2 * DS];
#pragma unroll
    for (int q = 0; q < 8; ++q) {
      float4v v = Bp[q];
#pragma unroll
      for (int j = 0; j < 4; ++j) BC[q * 4 + j] = v[j];
    }
    float du = dlt * ut;
    float yp = 0.f;
#pragma unroll
    for (int s = 0; s < DS; ++s) {
      h[s] = fmaf(__expf(dlt * Aj[s]), h[s], du * BC[s]);
      yp = fmaf(h[s], BC[DS + s], yp);
    }
    float zt = cvt(xz[(size_t)t * (2 * DI) + DI + d]);
    float gte = zt / (1.f + __expf(-zt));
    stv(&u[(size_t)t * DI + d], (yp + ut * Dd) * gte);
  }
}

// ---------------------------------------------------------------------------
extern "C" void kernel_launch(void* const* d_in, const int* in_sizes, int n_in,
                              void* d_out, int out_size, void* d_ws, size_t ws_size,
                              hipStream_t stream) {
  const float* hidden    = (const float*)d_in[0];
  const float* in_proj_w = (const float*)d_in[1];
  const float* conv_w    = (const float*)d_in[2];
  const float* conv_b    = (const float*)d_in[3];
  const float* x_proj_w  = (const float*)d_in[4];
  const float* dt_proj_w = (const float*)d_in[5];
  const float* dt_proj_b = (const float*)d_in[6];
  const float* A_log     = (const float*)d_in[7];
  const float* D_param   = (const float*)d_in[8];
  const float* out_proj_w= (const float*)d_in[9];
  float* out = (float*)d_out;

  // Workspace (131 MB, proven):
  //   xz 64MB bf16 | u 32MB bf16 | xdbl 3MB f32 | delta 32MB bf16
  size_t need = (size_t)TT * 4096 * sizeof(bf16) + (size_t)TT * DI * sizeof(bf16)
              + (size_t)TT * (DR + 2 * DS) * sizeof(float) + (size_t)TT * DI * sizeof(bf16);
  if (ws_size < need) return;

  bf16* xz     = (bf16*)d_ws;
  bf16* u      = xz + (size_t)TT * 2 * DI;
  float* xdbl  = (float*)(u + (size_t)TT * DI);
  bf16* delta  = (bf16*)(xdbl + (size_t)TT * (DR + 2 * DS));

  dim3 blk(256);

  // 1) xz = hidden @ in_proj_w^T   (MFMA, M=8192 N=4096 K=1024)
  gemm_mfma<float, bf16, 0><<<dim3(4096 / 128, TT / 128), blk, 0, stream>>>(
      hidden, DM, in_proj_w, DM, nullptr, xz, 2 * DI, DM);

  // 2) u = silu(causal_conv(x) + cb)  (vectorized)
  conv_silu<<<dim3(TT), blk, 0, stream>>>(xz, conv_w, conv_b, u);

  // 3) x_dbl = u @ x_proj_w^T      (MFMA split-K, partials in dead x-half)
  xproj_splitk<<<dim3(TT / 128, SK), blk, 0, stream>>>(u, x_proj_w, xz);
  xproj_reduce<<<dim3(TT * 96 / 256), blk, 0, stream>>>(xz, xdbl);

  // 4) delta = softplus(x_dbl[:, :64] @ dt_proj_w^T + b)  (MFMA, K=64)
  gemm_mfma<float, bf16, 1><<<dim3(DI / 128, TT / 128), blk, 0, stream>>>(
      xdbl, DR + 2 * DS, dt_proj_w, DR, dt_proj_b, delta, DI, DR);

  // 5) chunked selective scan (thread-per-chain); y -> in-place into u
  scan_local<<<dim3(8192 * NC / 256), blk, 0, stream>>>(delta, u, xdbl, xz, A_log);
  scan_fix<<<dim3(8192 / 16), blk, 0, stream>>>(xz, A_log);
  scan_final<<<dim3(8192 * NC / 256), blk, 0, stream>>>(delta, u, xdbl, xz, A_log, D_param);

  // 6) out = y @ out_proj_w^T      (MFMA, M=8192 N=1024 K=2048)
  gemm_mfma<bf16, float, 0><<<dim3(DM / 128, TT / 128), blk, 0, stream>>>(
      u, DI, out_proj_w, DI, nullptr, out, DM, DI);
}

// Round 7
// 535.248 us; speedup vs baseline: 8.2863x; 1.1381x over previous
//
#include <hip/hip_runtime.h>
#include <hip/hip_bf16.h>
#include <math.h>

// Problem constants
#define BB 4
#define LL 2048
#define DM 1024
#define DI 2048
#define DS 16
#define DR 64
#define KC 4
#define TT (BB * LL)   // 8192 tokens
#define NC 32          // scan chunks per sequence
#define CL (LL / NC)   // 64 steps per chunk
#define SK 8           // x_proj split-K factor

typedef __hip_bfloat16 bf16;
typedef short bf16x8 __attribute__((ext_vector_type(8)));
typedef short short8 __attribute__((ext_vector_type(8)));
typedef float f32x4 __attribute__((ext_vector_type(4)));
typedef float float4v __attribute__((ext_vector_type(4)));

__device__ __forceinline__ float cvt(float v) { return v; }
__device__ __forceinline__ float cvt(bf16 v) { return __bfloat162float(v); }
__device__ __forceinline__ float bf2f(short s) {
  union { short s; bf16 h; } c; c.s = s; return __bfloat162float(c.h);
}
__device__ __forceinline__ void stv(float* p, float v) { *p = v; }
__device__ __forceinline__ void stv(bf16* p, float v) { *p = __float2bfloat16(v); }
__device__ __forceinline__ short f2bf(float f) {
  union { bf16 h; short s; } u_; u_.h = __float2bfloat16(f); return u_.s;
}

// async global->LDS, 16B per lane; lds dest must be WAVE-UNIFORM base (HW adds lane*16)
__device__ __forceinline__ void gld16(const bf16* g, bf16* l) {
  __builtin_amdgcn_global_load_lds(
      (const __attribute__((address_space(1))) void*)g,
      (__attribute__((address_space(3))) void*)l, 16, 0, 0);
}

// ---------------------------------------------------------------------------
// f32 -> bf16 bulk convert (8 elems/thread, n8 = n/8)
// ---------------------------------------------------------------------------
__global__ __launch_bounds__(256) void cvt_bf16(
    const float* __restrict__ src, bf16* __restrict__ dst, int n8) {
  int i = blockIdx.x * 256 + threadIdx.x;
  if (i >= n8) return;
  const float4v* s = (const float4v*)(src + (size_t)i * 8);
  float4v v0 = s[0], v1 = s[1];
  short8 o;
#pragma unroll
  for (int j = 0; j < 4; ++j) { o[j] = f2bf(v0[j]); o[4 + j] = f2bf(v1[j]); }
  *(short8*)(dst + (size_t)i * 8) = o;
}

// ---------------------------------------------------------------------------
// Pure-bf16 MFMA GEMM (m97 structure): C[M,N] = A[M,K] * W[N,K]^T.
// 128x128 tile, 4 waves (2x2 of 64x64), BK=32, LINEAR LDS [128][32] (no pad,
// required by global_load_lds), 4 global_load_lds dwordx4 per wave per K-step,
// 2-barrier loop. Dims must divide 128/128/32.
// ---------------------------------------------------------------------------
template <typename TC>
__global__ __launch_bounds__(256) void gemm_bf16(
    const bf16* __restrict__ A, int lda,
    const bf16* __restrict__ W, int ldw,
    TC* __restrict__ C, int ldc, int Kd) {
  __shared__ bf16 As[128 * 32];
  __shared__ bf16 Bs[128 * 32];
  int tid = threadIdx.x;
  int bm = blockIdx.y * 128, bn = blockIdx.x * 128;
  int wave = tid >> 6, lane = tid & 63;
  int wm = (wave >> 1) * 64, wn = (wave & 1) * 64;
  int lr = lane & 15, kg = lane >> 4;

  // staging: assignment a = l*256 + wave*64 + lane -> LDS byte a*16
  // row = a>>2 = l*64 + wave*16 + lane/4, kcol = (lane&3)*8
  int srow = wave * 16 + (lane >> 2);
  int kc = (lane & 3) * 8;
  const bf16* gA0 = A + (size_t)(bm + srow) * lda + kc;
  const bf16* gA1 = gA0 + (size_t)64 * lda;
  const bf16* gW0 = W + (size_t)(bn + srow) * ldw + kc;
  const bf16* gW1 = gW0 + (size_t)64 * ldw;
  bf16* lA0 = &As[wave * 512];          // wave-uniform LDS bases
  bf16* lA1 = &As[2048 + wave * 512];
  bf16* lB0 = &Bs[wave * 512];
  bf16* lB1 = &Bs[2048 + wave * 512];

  f32x4 acc[4][4] = {};

  for (int k0 = 0; k0 < Kd; k0 += 32) {
    __syncthreads();                    // prev iter's LDS reads done
    gld16(gA0 + k0, lA0);
    gld16(gA1 + k0, lA1);
    gld16(gW0 + k0, lB0);
    gld16(gW1 + k0, lB1);
    __syncthreads();                    // DMA drained (vmcnt(0) before barrier)

    bf16x8 af[4], bfr[4];
#pragma unroll
    for (int i = 0; i < 4; ++i)
      af[i] = *(const bf16x8*)&As[(wm + i * 16 + lr) * 32 + kg * 8];
#pragma unroll
    for (int j = 0; j < 4; ++j)
      bfr[j] = *(const bf16x8*)&Bs[(wn + j * 16 + lr) * 32 + kg * 8];
#pragma unroll
    for (int i = 0; i < 4; ++i)
#pragma unroll
      for (int j = 0; j < 4; ++j)
        acc[i][j] = __builtin_amdgcn_mfma_f32_16x16x32_bf16(af[i], bfr[j], acc[i][j], 0, 0, 0);
  }

  // D: row=(lane>>4)*4+rr, col=lane&15 [m89-verified]
#pragma unroll
  for (int i = 0; i < 4; ++i) {
    int row0 = bm + wm + i * 16 + kg * 4;
#pragma unroll
    for (int j = 0; j < 4; ++j) {
      int col = bn + wn + j * 16 + lr;
#pragma unroll
      for (int rr = 0; rr < 4; ++rr)
        stv(&C[(size_t)(row0 + rr) * ldc + col], acc[i][j][rr]);
    }
  }
}

// ---------------------------------------------------------------------------
// Reg-staged MFMA GEMM with f32->bf16 convert (kept for dt_proj, K=64)
// + bias+softplus epilogue.
// ---------------------------------------------------------------------------
__device__ __forceinline__ void loadcvt16(const float* p, short* d) {
#pragma unroll
  for (int i = 0; i < 4; ++i) {
    float4v v = ((const float4v*)p)[i];
#pragma unroll
    for (int j = 0; j < 4; ++j) d[i * 4 + j] = f2bf(v[j]);
  }
}
__device__ __forceinline__ void loadcvt16(const bf16* p, short* d) {
  ((short8*)d)[0] = ((const short8*)p)[0];
  ((short8*)d)[1] = ((const short8*)p)[1];
}

template <typename TA, typename TC, int EPI>
__global__ __launch_bounds__(256) void gemm_mfma(
    const TA* __restrict__ A, int lda,
    const float* __restrict__ W, int ldw,
    const float* __restrict__ bias,
    TC* __restrict__ C, int ldc, int Kd) {
  __shared__ short As[128 * 40];
  __shared__ short Bs[128 * 40];
  int tid = threadIdx.x;
  int bm = blockIdx.y * 128, bn = blockIdx.x * 128;

  int r = tid >> 1, hh = (tid & 1) * 16;
  const TA* ga = A + (size_t)(bm + r) * lda + hh;
  const float* gw = W + (size_t)(bn + r) * ldw + hh;

  int wave = tid >> 6, lane = tid & 63;
  int wm = (wave >> 1) * 64, wn = (wave & 1) * 64;
  int lr = lane & 15, kg = lane >> 4;

  f32x4 acc[4][4] = {};

  for (int k0 = 0; k0 < Kd; k0 += 32) {
    short abuf[16], wbuf[16];
    loadcvt16(ga + k0, abuf);
    loadcvt16(gw + k0, wbuf);
    __syncthreads();
    ((short8*)&As[r * 40 + hh])[0] = ((short8*)abuf)[0];
    ((short8*)&As[r * 40 + hh])[1] = ((short8*)abuf)[1];
    ((short8*)&Bs[r * 40 + hh])[0] = ((short8*)wbuf)[0];
    ((short8*)&Bs[r * 40 + hh])[1] = ((short8*)wbuf)[1];
    __syncthreads();

    bf16x8 af[4], bfr[4];
#pragma unroll
    for (int i = 0; i < 4; ++i)
      af[i] = *(const bf16x8*)&As[(wm + i * 16 + lr) * 40 + kg * 8];
#pragma unroll
    for (int j = 0; j < 4; ++j)
      bfr[j] = *(const bf16x8*)&Bs[(wn + j * 16 + lr) * 40 + kg * 8];
#pragma unroll
    for (int i = 0; i < 4; ++i)
#pragma unroll
      for (int j = 0; j < 4; ++j)
        acc[i][j] = __builtin_amdgcn_mfma_f32_16x16x32_bf16(af[i], bfr[j], acc[i][j], 0, 0, 0);
  }

#pragma unroll
  for (int i = 0; i < 4; ++i) {
    int row0 = bm + wm + i * 16 + kg * 4;
#pragma unroll
    for (int j = 0; j < 4; ++j) {
      int col = bn + wn + j * 16 + lr;
#pragma unroll
      for (int rr = 0; rr < 4; ++rr) {
        float v = acc[i][j][rr];
        if (EPI == 1) {
          v += bias[col];
          v = (v > 20.f) ? v : log1pf(expf(v));
        }
        stv(&C[(size_t)(row0 + rr) * ldc + col], v);
      }
    }
  }
}

// ---------------------------------------------------------------------------
// Scan-state / split-K partial aliasing into the dead x-half of xz.
// ---------------------------------------------------------------------------
__device__ __forceinline__ float* stslot(bf16* xz, int idx) {
  int t = idx >> 10, j = idx & 1023;
  return (float*)((char*)xz + (size_t)t * 8192) + j;
}
#define SUMD_BASE (8192 * NC * DS)

// ---------------------------------------------------------------------------
// x_proj split-K (unchanged)
// ---------------------------------------------------------------------------
__global__ __launch_bounds__(256) void xproj_splitk(
    const bf16* __restrict__ u, const float* __restrict__ W,
    bf16* __restrict__ xz) {
  __shared__ short As[128 * 40];
  __shared__ short Bs[96 * 40];
  int tid = threadIdx.x;
  int bm = blockIdx.x * 128;
  int sk = blockIdx.y;
  int kb = sk * (DI / SK);

  int r = tid >> 1, hh = (tid & 1) * 16;
  const bf16* ga = u + (size_t)(bm + r) * DI + kb + hh;
  const float* gw = W + (size_t)r * DI + kb + hh;

  int wave = tid >> 6, lane = tid & 63;
  int wm = wave * 32;
  int lr = lane & 15, kg = lane >> 4;

  f32x4 acc[2][6] = {};

  for (int k0 = 0; k0 < DI / SK; k0 += 32) {
    short abuf[16], wbuf[16];
    loadcvt16(ga + k0, abuf);
    if (r < 96) loadcvt16(gw + k0, wbuf);
    __syncthreads();
    ((short8*)&As[r * 40 + hh])[0] = ((short8*)abuf)[0];
    ((short8*)&As[r * 40 + hh])[1] = ((short8*)abuf)[1];
    if (r < 96) {
      ((short8*)&Bs[r * 40 + hh])[0] = ((short8*)wbuf)[0];
      ((short8*)&Bs[r * 40 + hh])[1] = ((short8*)wbuf)[1];
    }
    __syncthreads();

    bf16x8 af[2], bfr[6];
#pragma unroll
    for (int i = 0; i < 2; ++i)
      af[i] = *(const bf16x8*)&As[(wm + i * 16 + lr) * 40 + kg * 8];
#pragma unroll
    for (int j = 0; j < 6; ++j)
      bfr[j] = *(const bf16x8*)&Bs[(j * 16 + lr) * 40 + kg * 8];
#pragma unroll
    for (int i = 0; i < 2; ++i)
#pragma unroll
      for (int j = 0; j < 6; ++j)
        acc[i][j] = __builtin_amdgcn_mfma_f32_16x16x32_bf16(af[i], bfr[j], acc[i][j], 0, 0, 0);
  }

#pragma unroll
  for (int i = 0; i < 2; ++i) {
#pragma unroll
    for (int j = 0; j < 6; ++j) {
      int col = j * 16 + lr;
#pragma unroll
      for (int rr = 0; rr < 4; ++rr) {
        int row = bm + wm + i * 16 + kg * 4 + rr;
        *stslot(xz, (sk * 8192 + row) * 96 + col) = acc[i][j][rr];
      }
    }
  }
}

__global__ __launch_bounds__(256) void xproj_reduce(
    bf16* __restrict__ xz, float* __restrict__ xdbl) {
  int gid = blockIdx.x * 256 + threadIdx.x;
  float s = 0.f;
#pragma unroll
  for (int sk = 0; sk < SK; ++sk)
    s += *stslot(xz, sk * (8192 * 96) + gid);
  xdbl[gid] = s;
}

// ---------------------------------------------------------------------------
// Depthwise causal conv1d (K=4) + bias + SiLU — vectorized.
// ---------------------------------------------------------------------------
__global__ __launch_bounds__(256) void conv_silu(
    const bf16* __restrict__ xz, const float* __restrict__ cw,
    const float* __restrict__ cb, bf16* __restrict__ u) {
  int t = blockIdx.x;
  int d0 = threadIdx.x * 8;
  int l = t & (LL - 1);

  float acc[8];
  float4v c0 = *(const float4v*)&cb[d0];
  float4v c1 = *(const float4v*)&cb[d0 + 4];
#pragma unroll
  for (int j = 0; j < 4; ++j) { acc[j] = c0[j]; acc[4 + j] = c1[j]; }

  float wv[32];
  const float4v* wp = (const float4v*)&cw[d0 * 4];
#pragma unroll
  for (int q = 0; q < 8; ++q) {
    float4v v = wp[q];
#pragma unroll
    for (int j = 0; j < 4; ++j) wv[q * 4 + j] = v[j];
  }

#pragma unroll
  for (int k = 0; k < KC; ++k) {
    int lt = l - (KC - 1) + k;
    if (lt >= 0) {
      short8 xv = *(const short8*)&xz[(size_t)(t - (KC - 1) + k) * (2 * DI) + d0];
#pragma unroll
      for (int q = 0; q < 8; ++q)
        acc[q] = fmaf(bf2f(xv[q]), wv[q * 4 + k], acc[q]);
    }
  }

  short8 ov;
#pragma unroll
  for (int q = 0; q < 8; ++q) {
    float s = acc[q] / (1.f + __expf(-acc[q]));
    ov[q] = f2bf(s);
  }
  *(short8*)&u[(size_t)t * DI + d0] = ov;
}

// ---------------------------------------------------------------------------
// Chunked selective scan, thread-per-chain (unchanged).
// ---------------------------------------------------------------------------
__global__ __launch_bounds__(256) void scan_local(
    const bf16* __restrict__ delta, const bf16* __restrict__ u,
    const float* __restrict__ xdbl, bf16* __restrict__ xz,
    const float* __restrict__ A_log) {
  int g = blockIdx.x * 256 + threadIdx.x;
  int d = g & (DI - 1);
  int b = (g >> 11) & (BB - 1);
  int c = g >> 13;
  int chain = (b << 11) | d;

  float Aj[DS];
  const float4v* Ap = (const float4v*)&A_log[d * DS];
#pragma unroll
  for (int i = 0; i < 4; ++i) {
    float4v v = Ap[i];
#pragma unroll
    for (int j = 0; j < 4; ++j) Aj[i * 4 + j] = -__expf(v[j]);
  }

  float h[DS];
#pragma unroll
  for (int s = 0; s < DS; ++s) h[s] = 0.f;
  float sd = 0.f;
  int t0 = b * LL + c * CL;

  for (int i = 0; i < CL; ++i) {
    int t = t0 + i;
    float dlt = cvt(delta[(size_t)t * DI + d]);
    float ut = cvt(u[(size_t)t * DI + d]);
    const float4v* Bp = (const float4v*)&xdbl[(size_t)t * (DR + 2 * DS) + DR];
    float Bv[DS];
#pragma unroll
    for (int q = 0; q < 4; ++q) {
      float4v v = Bp[q];
#pragma unroll
      for (int j = 0; j < 4; ++j) Bv[q * 4 + j] = v[j];
    }
    float du = dlt * ut;
    sd += dlt;
#pragma unroll
    for (int s = 0; s < DS; ++s)
      h[s] = fmaf(__expf(dlt * Aj[s]), h[s], du * Bv[s]);
  }

  float4v* hv = (float4v*)stslot(xz, (chain * NC + c) * DS);
#pragma unroll
  for (int q = 0; q < 4; ++q) {
    float4v v;
#pragma unroll
    for (int j = 0; j < 4; ++j) v[j] = h[q * 4 + j];
    hv[q] = v;
  }
  *stslot(xz, SUMD_BASE + chain * NC + c) = sd;
}

__global__ __launch_bounds__(256) void scan_fix(
    bf16* __restrict__ xz, const float* __restrict__ A_log) {
  int lane = threadIdx.x & 15;
  int chain = blockIdx.x * 16 + (threadIdx.x >> 4);
  int d = chain & (DI - 1);
  float Aj = -__expf(A_log[d * DS + lane]);
  float carry = 0.f;
  for (int c = 0; c < NC; ++c) {
    float* hp = stslot(xz, (chain * NC + c) * DS + lane);
    float sd = *stslot(xz, SUMD_BASE + chain * NC + c);
    float he = *hp;
    *hp = carry;
    carry = fmaf(__expf(Aj * sd), carry, he);
  }
}

__global__ __launch_bounds__(256) void scan_final(
    const bf16* __restrict__ delta, bf16* __restrict__ u,
    const float* __restrict__ xdbl, bf16* __restrict__ xz,
    const float* __restrict__ A_log, const float* __restrict__ Dp) {
  int g = blockIdx.x * 256 + threadIdx.x;
  int d = g & (DI - 1);
  int b = (g >> 11) & (BB - 1);
  int c = g >> 13;
  int chain = (b << 11) | d;

  float Aj[DS];
  const float4v* Ap = (const float4v*)&A_log[d * DS];
#pragma unroll
  for (int i = 0; i < 4; ++i) {
    float4v v = Ap[i];
#pragma unroll
    for (int j = 0; j < 4; ++j) Aj[i * 4 + j] = -__expf(v[j]);
  }
  float Dd = Dp[d];

  float h[DS];
  const float4v* hv = (const float4v*)stslot(xz, (chain * NC + c) * DS);
#pragma unroll
  for (int q = 0; q < 4; ++q) {
    float4v v = hv[q];
#pragma unroll
    for (int j = 0; j < 4; ++j) h[q * 4 + j] = v[j];
  }

  int t0 = b * LL + c * CL;
  for (int i = 0; i < CL; ++i) {
    int t = t0 + i;
    float dlt = cvt(delta[(size_t)t * DI + d]);
    float ut = cvt(u[(size_t)t * DI + d]);
    const float4v* Bp = (const float4v*)&xdbl[(size_t)t * (DR + 2 * DS) + DR];
    float BC[2 * DS];
#pragma unroll
    for (int q = 0; q < 8; ++q) {
      float4v v = Bp[q];
#pragma unroll
      for (int j = 0; j < 4; ++j) BC[q * 4 + j] = v[j];
    }
    float du = dlt * ut;
    float yp = 0.f;
#pragma unroll
    for (int s = 0; s < DS; ++s) {
      h[s] = fmaf(__expf(dlt * Aj[s]), h[s], du * BC[s]);
      yp = fmaf(h[s], BC[DS + s], yp);
    }
    float zt = cvt(xz[(size_t)t * (2 * DI) + DI + d]);
    float gte = zt / (1.f + __expf(-zt));
    stv(&u[(size_t)t * DI + d], (yp + ut * Dd) * gte);
  }
}

// ---------------------------------------------------------------------------
extern "C" void kernel_launch(void* const* d_in, const int* in_sizes, int n_in,
                              void* d_out, int out_size, void* d_ws, size_t ws_size,
                              hipStream_t stream) {
  const float* hidden    = (const float*)d_in[0];
  const float* in_proj_w = (const float*)d_in[1];
  const float* conv_w    = (const float*)d_in[2];
  const float* conv_b    = (const float*)d_in[3];
  const float* x_proj_w  = (const float*)d_in[4];
  const float* dt_proj_w = (const float*)d_in[5];
  const float* dt_proj_b = (const float*)d_in[6];
  const float* A_log     = (const float*)d_in[7];
  const float* D_param   = (const float*)d_in[8];
  const float* out_proj_w= (const float*)d_in[9];
  float* out = (float*)d_out;

  // Workspace (131 MB, proven):
  //   xz 64MB bf16 | u 32MB bf16 | xdbl 3MB f32 | delta 32MB bf16
  // Aliases: hidden_bf16+in_proj_w_bf16 live in u region until conv writes it;
  //          out_proj_w_bf16 lives in delta region after scan_final.
  size_t need = (size_t)TT * 4096 * sizeof(bf16) + (size_t)TT * DI * sizeof(bf16)
              + (size_t)TT * (DR + 2 * DS) * sizeof(float) + (size_t)TT * DI * sizeof(bf16);
  if (ws_size < need) return;

  bf16* xz     = (bf16*)d_ws;
  bf16* u      = xz + (size_t)TT * 2 * DI;
  float* xdbl  = (float*)(u + (size_t)TT * DI);
  bf16* delta  = (bf16*)(xdbl + (size_t)TT * (DR + 2 * DS));

  bf16* hbf  = u;                         // 8192x1024 bf16 (16MB), dead after step 1
  bf16* wbf  = u + (size_t)TT * DM;       // 4096x1024 bf16 (8MB),  dead after step 1
  bf16* opbf = delta;                     // 1024x2048 bf16 (4MB),  written after scan

  dim3 blk(256);

  // 0) pre-convert A and W for in_proj
  cvt_bf16<<<dim3(TT * DM / 8 / 256), blk, 0, stream>>>(hidden, hbf, TT * DM / 8);
  cvt_bf16<<<dim3(2 * DI * DM / 8 / 256), blk, 0, stream>>>(in_proj_w, wbf, 2 * DI * DM / 8);

  // 1) xz = hidden @ in_proj_w^T   (bf16 gload_lds GEMM, M=8192 N=4096 K=1024)
  gemm_bf16<bf16><<<dim3(4096 / 128, TT / 128), blk, 0, stream>>>(
      hbf, DM, wbf, DM, xz, 2 * DI, DM);

  // 2) u = silu(causal_conv(x) + cb)   (overwrites hbf/wbf — both dead)
  conv_silu<<<dim3(TT), blk, 0, stream>>>(xz, conv_w, conv_b, u);

  // 3) x_dbl = u @ x_proj_w^T      (MFMA split-K, partials in dead x-half)
  xproj_splitk<<<dim3(TT / 128, SK), blk, 0, stream>>>(u, x_proj_w, xz);
  xproj_reduce<<<dim3(TT * 96 / 256), blk, 0, stream>>>(xz, xdbl);

  // 4) delta = softplus(x_dbl[:, :64] @ dt_proj_w^T + b)  (MFMA, K=64)
  gemm_mfma<float, bf16, 1><<<dim3(DI / 128, TT / 128), blk, 0, stream>>>(
      xdbl, DR + 2 * DS, dt_proj_w, DR, dt_proj_b, delta, DI, DR);

  // 5) chunked selective scan (thread-per-chain); y -> in-place into u
  scan_local<<<dim3(8192 * NC / 256), blk, 0, stream>>>(delta, u, xdbl, xz, A_log);
  scan_fix<<<dim3(8192 / 16), blk, 0, stream>>>(xz, A_log);
  scan_final<<<dim3(8192 * NC / 256), blk, 0, stream>>>(delta, u, xdbl, xz, A_log, D_param);

  // 5b) convert out_proj_w -> bf16 into delta region (delta dead now)
  cvt_bf16<<<dim3(DM * DI / 8 / 256), blk, 0, stream>>>(out_proj_w, opbf, DM * DI / 8);

  // 6) out = y @ out_proj_w^T      (bf16 gload_lds GEMM, M=8192 N=1024 K=2048)
  gemm_bf16<float><<<dim3(DM / 128, TT / 128), blk, 0, stream>>>(
      u, DI, opbf, DI, out, DM, DI);
}